// Round 1
// baseline (335.176 us; speedup 1.0000x reference)
//
#include <hip/hip_runtime.h>
#include <hip/hip_bf16.h>

// Problem constants (from reference): B=2, C=1, X=128, K=16
#define VOL (128 * 128 * 128)       // 2,097,152 elements per (b,c) volume
#define BATCH 2
#define KSAMP 16

// Each thread processes 4 consecutive floats (float4, 16B coalesced).
// eps layout: [K, B, C, X, X, X] -> k-stride = B*VOL.
// Row j (1..15) of the loop samples is KEPT iff j > 2*ncoils[b]+1,
// i.e. j >= 2*ncoils[b]+2. eps[0] is always included.
__global__ __launch_bounds__(256) void RandomChiNoise_40235253629142_kernel(
    const float* __restrict__ image,
    const float* __restrict__ sigma,
    const float* __restrict__ eps,
    const int* __restrict__ ncoils,
    float* __restrict__ out) {

    const int b = blockIdx.y;
    const long long t = (long long)blockIdx.x * blockDim.x + threadIdx.x;
    const long long idx4 = t * 4;
    if (idx4 >= VOL) return;

    const long long base = (long long)b * VOL + idx4;
    const long long kstride = (long long)BATCH * VOL;

    // eps[0]^2 always contributes
    float4 e0 = *(const float4*)(eps + base);
    float ax = e0.x * e0.x;
    float ay = e0.y * e0.y;
    float az = e0.z * e0.z;
    float aw = e0.w * e0.w;

    const int nc = ncoils[b];
    const int jstart = 2 * nc + 2;   // first kept loop-sample index (may be >=16 -> none)

    for (int j = jstart; j < KSAMP; ++j) {
        float4 e = *(const float4*)(eps + (long long)j * kstride + base);
        ax += e.x * e.x;
        ay += e.y * e.y;
        az += e.z * e.z;
        aw += e.w * e.w;
    }

    const float s = sigma[b];        // sigma shape (B, C=1)
    const float s2 = s * s;

    float4 img = *(const float4*)(image + base);
    float4 o;
    o.x = img.x + sqrtf(s2 * ax);
    o.y = img.y + sqrtf(s2 * ay);
    o.z = img.z + sqrtf(s2 * az);
    o.w = img.w + sqrtf(s2 * aw);

    *(float4*)(out + base) = o;
}

extern "C" void kernel_launch(void* const* d_in, const int* in_sizes, int n_in,
                              void* d_out, int out_size, void* d_ws, size_t ws_size,
                              hipStream_t stream) {
    const float* image  = (const float*)d_in[0];
    const float* sigma  = (const float*)d_in[1];
    const float* eps    = (const float*)d_in[2];
    const int*   ncoils = (const int*)d_in[3];
    float* out = (float*)d_out;

    const int threads = 256;
    const int blocks_x = (VOL / 4 + threads - 1) / threads;  // 2048
    dim3 grid(blocks_x, BATCH, 1);
    RandomChiNoise_40235253629142_kernel<<<grid, threads, 0, stream>>>(
        image, sigma, eps, ncoils, out);
}

// Round 3
// 329.766 us; speedup vs baseline: 1.0164x; 1.0164x over previous
//
#include <hip/hip_runtime.h>
#include <hip/hip_bf16.h>

// Problem constants (from reference): B=2, C=1, X=128, K=16
#define VOL (128 * 128 * 128)       // 2,097,152 elements per (b,c) volume
#define BATCH 2
#define KSAMP 16

// Native clang vector type: __builtin_nontemporal_load/store require a real
// vector type, not HIP_vector_type<float,4> (a struct).
typedef float floatx4 __attribute__((ext_vector_type(4)));

// Each thread processes 8 consecutive floats (2x 16B, 32B total).
// eps layout: [K, B, C, X, X, X] -> k-stride = B*VOL.
// Loop sample j (1..15) is KEPT iff j > 2*ncoils[b]+1, i.e. j >= 2*ncoils[b]+2.
// eps[0] is always included.
// Grid is 1-D with batch interleaved in the low bit of blockIdx.x so the
// data-dependent per-batch work (0..14 kept rows) is balanced across CUs.
__global__ __launch_bounds__(256) void RandomChiNoise_40235253629142_kernel(
    const float* __restrict__ image,
    const float* __restrict__ sigma,
    const float* __restrict__ eps,
    const int* __restrict__ ncoils,
    float* __restrict__ out) {

    const int b = blockIdx.x & 1;            // interleave batches
    const int chunk = blockIdx.x >> 1;       // 0..1023 per batch
    const long long idx = ((long long)chunk * blockDim.x + threadIdx.x) * 8;
    const long long base = (long long)b * VOL + idx;
    const long long kstride = (long long)BATCH * VOL;

    const floatx4* p0 = (const floatx4*)(eps + base);
    floatx4 e0a = __builtin_nontemporal_load(p0);
    floatx4 e0b = __builtin_nontemporal_load(p0 + 1);

    floatx4 acca = e0a * e0a;
    floatx4 accb = e0b * e0b;

    const int nc = ncoils[b];
    const int jstart = 2 * nc + 2;           // first kept loop-sample index

    for (int j = jstart; j < KSAMP; ++j) {
        const floatx4* p = (const floatx4*)(eps + (long long)j * kstride + base);
        floatx4 ea = __builtin_nontemporal_load(p);
        floatx4 eb = __builtin_nontemporal_load(p + 1);
        acca += ea * ea;
        accb += eb * eb;
    }

    const float s = sigma[b];                // sigma shape (B, C=1)
    const float s2 = s * s;

    const floatx4* pi = (const floatx4*)(image + base);
    floatx4 ia = __builtin_nontemporal_load(pi);
    floatx4 ib = __builtin_nontemporal_load(pi + 1);

    floatx4 oa, ob;
    oa.x = ia.x + sqrtf(s2 * acca.x); oa.y = ia.y + sqrtf(s2 * acca.y);
    oa.z = ia.z + sqrtf(s2 * acca.z); oa.w = ia.w + sqrtf(s2 * acca.w);
    ob.x = ib.x + sqrtf(s2 * accb.x); ob.y = ib.y + sqrtf(s2 * accb.y);
    ob.z = ib.z + sqrtf(s2 * accb.z); ob.w = ib.w + sqrtf(s2 * accb.w);

    floatx4* po = (floatx4*)(out + base);
    __builtin_nontemporal_store(oa, po);
    __builtin_nontemporal_store(ob, po + 1);
}

extern "C" void kernel_launch(void* const* d_in, const int* in_sizes, int n_in,
                              void* d_out, int out_size, void* d_ws, size_t ws_size,
                              hipStream_t stream) {
    const float* image  = (const float*)d_in[0];
    const float* sigma  = (const float*)d_in[1];
    const float* eps    = (const float*)d_in[2];
    const int*   ncoils = (const int*)d_in[3];
    float* out = (float*)d_out;

    const int threads = 256;
    // 8 floats per thread -> VOL/(8*256) = 1024 blocks per batch, x2 batches
    const int blocks = (VOL / (8 * threads)) * BATCH;  // 2048
    RandomChiNoise_40235253629142_kernel<<<blocks, threads, 0, stream>>>(
        image, sigma, eps, ncoils, out);
}